// Round 9
// baseline (106.669 us; speedup 1.0000x reference)
//
#include <hip/hip_runtime.h>
#include <stdint.h>
#include <stddef.h>

typedef __bf16 bf16_t;
typedef __bf16 bf16x8 __attribute__((ext_vector_type(8)));
typedef float  f32x4  __attribute__((ext_vector_type(4)));

#define NIMG 16
#define CIN  128
#define COUT 128
#define HH   56
#define WW   56
#define HW   (HH * WW)       // 3136
#define CDIM 58              // staged c extent: c = w+1, w = -1..56
#define CSTR 40              // LDS c-stride (bf16): 80 B -> 2-way banks (R4-verified free)
#define TILE (4 * CDIM * CSTR)   // 9280 bf16 = 18,560 B per buffer
#define ROWPAIRS 28
#define CHUNK_UNITS 928      // 4 rows x 58 c x 4 cig(8ci) per 32-ci chunk

// ---------- prologue: W[co][ci][3][3] fp32 -> Wt2 fragment-major bf16 (R5-verified) ----------
// rec = (khkw*4+chunk)*8 + (co>>4); element (lane=l4*16+l15, j) =
//   W[co=(co>>4)*16+l15][ci=chunk*32+l4*8+j][khkw]   (1 KB lane-contiguous bursts)
__global__ void wtrans_kernel(const float* __restrict__ w, bf16_t* __restrict__ wt2) {
    int idx = blockIdx.x * 256 + threadIdx.x;    // 16384 threads: one (co,ci) each
    int co = idx >> 7, ci = idx & 127;
    const float* src = w + (size_t)idx * 9;
    float v[9];
#pragma unroll
    for (int k = 0; k < 9; ++k) v[k] = src[k];
    int chunk = ci >> 5, l4 = (ci >> 3) & 3, j = ci & 7;
    int cotile = co >> 4, l15 = co & 15;
    int lane = l4 * 16 + l15;
#pragma unroll
    for (int k = 0; k < 9; ++k) {
        size_t rec = (size_t)((k * 4 + chunk) * 8 + cotile);
        wt2[rec * 512 + lane * 8 + j] = (bf16_t)v[k];
    }
}

// ---------- fused conv, chunk-streamed: block = (n, 2 rows) x 128 co, 256 thr ----------
// 4 waves (ws x wc), each 64sp x 64co, full K. Double-buffered 32-ci LDS tiles;
// staging of chunk c+1 interleaved with the 9 compute phases of chunk c.

// phase Q = chunk*9 + khkw; A-frag record offset for Q (wc/tc folded into wpbase):
#define AOFF(Q) ((size_t)((((Q) % 9) * 4 + (Q) / 9) * 8) * 512)

#define DO_PHASE(Q) do {                                                              \
    const int kh_ = ((Q) % 9) / 3, kw_ = ((Q) % 9) % 3;                               \
    const bf16_t* lb_ = cur + ((ws + kh_) * CDIM) * CSTR + l4 * 8;                    \
    _Pragma("unroll")                                                                 \
    for (int ts = 0; ts < 4; ++ts) {                                                  \
        int cb_ = ts * 16 + l15 + kw_;                                                \
        if (cb_ > 57) cb_ = 57;   /* only lanes whose outputs are discarded */        \
        bf16x8 bfm_ = *(const bf16x8*)(lb_ + cb_ * CSTR);                             \
        _Pragma("unroll")                                                             \
        for (int tc = 0; tc < 4; ++tc)                                                \
            acc[tc][ts] = __builtin_amdgcn_mfma_f32_16x16x32_bf16(                    \
                af[(Q) & 1][tc], bfm_, acc[tc][ts], 0, 0, 0);                         \
    }                                                                                 \
    if ((Q) + 2 < 36) {   /* prefetch Q+2 into the slot just freed */                 \
        const bf16_t* wp_ = wpbase + AOFF((Q) + 2);                                   \
        _Pragma("unroll")                                                             \
        for (int tc = 0; tc < 4; ++tc)                                                \
            af[(Q) & 1][tc] = *(const bf16x8*)(wp_ + (size_t)tc * 512);               \
    }                                                                                 \
} while (0)

#define STG_LOAD(P, CH) do {                                                          \
    int G_ = (P) * 256 + tid;                                                         \
    if ((P) < 3 || G_ < CHUNK_UNITS) {                                                \
        int cig_ = G_ / 232, rem_ = G_ - cig_ * 232;                                  \
        int rr_ = rem_ / 58, c_ = rem_ - rr_ * 58;                                    \
        int ri_ = h0 - 1 + rr_, w_ = c_ - 1;                                          \
        if (ri_ >= 0 && ri_ < HH && w_ >= 0 && w_ < WW) {                             \
            const float* s_ = inb + ((size_t)((CH) * 32 + cig_ * 8) * HH + ri_) * WW + w_; \
            _Pragma("unroll")                                                         \
            for (int j = 0; j < 8; ++j) sv[(P) & 1][j] = s_[(size_t)j * HW];          \
        } else {                                                                      \
            _Pragma("unroll")                                                         \
            for (int j = 0; j < 8; ++j) sv[(P) & 1][j] = 0.f;                         \
        }                                                                             \
    }                                                                                 \
} while (0)

#define STG_WRITE(P, DST) do {                                                        \
    int G_ = (P) * 256 + tid;                                                         \
    if ((P) < 3 || G_ < CHUNK_UNITS) {                                                \
        int cig_ = G_ / 232, rem_ = G_ - cig_ * 232;                                  \
        int rr_ = rem_ / 58, c_ = rem_ - rr_ * 58;                                    \
        uint32_t u_[8];                                                               \
        _Pragma("unroll")                                                             \
        for (int j = 0; j < 8; ++j) { bf16_t b_ = (bf16_t)sv[(P) & 1][j]; u_[j] = *(const uint16_t*)&b_; } \
        uint4 o_;                                                                     \
        o_.x = u_[0] | (u_[1] << 16); o_.y = u_[2] | (u_[3] << 16);                   \
        o_.z = u_[4] | (u_[5] << 16); o_.w = u_[6] | (u_[7] << 16);                   \
        *(uint4*)&(DST)[(rr_ * CDIM + c_) * CSTR + cig_ * 8] = o_;                    \
    }                                                                                 \
} while (0)

// one chunk: 9 compute phases on `cur`, staging of chunk CH+1 into `nxt` interleaved
#define CH_BODY(CH) do {                                                              \
    bf16_t* cur = lds + ((CH) & 1) * TILE;                                            \
    bf16_t* nxt = lds + (((CH) + 1) & 1) * TILE;                                      \
    (void)nxt;                                                                        \
    DO_PHASE((CH) * 9 + 0);                                                           \
    if ((CH) < 3) STG_LOAD(0, (CH) + 1);                                              \
    DO_PHASE((CH) * 9 + 1);                                                           \
    DO_PHASE((CH) * 9 + 2);                                                           \
    if ((CH) < 3) { STG_WRITE(0, nxt); STG_LOAD(1, (CH) + 1); }                       \
    DO_PHASE((CH) * 9 + 3);                                                           \
    DO_PHASE((CH) * 9 + 4);                                                           \
    if ((CH) < 3) { STG_WRITE(1, nxt); STG_LOAD(2, (CH) + 1); }                       \
    DO_PHASE((CH) * 9 + 5);                                                           \
    DO_PHASE((CH) * 9 + 6);                                                           \
    if ((CH) < 3) { STG_WRITE(2, nxt); STG_LOAD(3, (CH) + 1); }                       \
    DO_PHASE((CH) * 9 + 7);                                                           \
    if ((CH) < 3) STG_WRITE(3, nxt);                                                  \
    DO_PHASE((CH) * 9 + 8);                                                           \
    __syncthreads();                                                                  \
} while (0)

__global__ __launch_bounds__(256, 3)
void conv_fused_kernel(const float* __restrict__ in, const bf16_t* __restrict__ Wt2,
                       const float* __restrict__ bias, float* __restrict__ out) {
    __shared__ __align__(16) bf16_t lds[2 * TILE];   // 37,120 B -> 3 blocks/CU (VGPR-limited)

    const int bx = blockIdx.x;
    const int n  = bx / ROWPAIRS;
    const int h0 = (bx % ROWPAIRS) * 2;          // output rows h0, h0+1; input rows h0-1..h0+2

    const int tid  = threadIdx.x;
    const int lane = tid & 63;
    const int wave = tid >> 6;                   // 0..3
    const int ws  = wave & 1;                    // output row within pair
    const int wc  = wave >> 1;                   // co half (64)
    const int l15 = lane & 15;
    const int l4  = lane >> 4;

    const float* inb = in + (size_t)n * CIN * HW;

    float sv[2][8];                              // staging double-buffer regs

    // ---- stage chunk 0 into buffer 0 (serial head, once per block)
    STG_LOAD(0, 0);
    STG_LOAD(1, 0);
    STG_WRITE(0, lds);
    STG_LOAD(2, 0);
    STG_WRITE(1, lds);
    STG_LOAD(3, 0);
    STG_WRITE(2, lds);
    STG_WRITE(3, lds);

    f32x4 acc[4][4];                             // [co tile][sp tile]
#pragma unroll
    for (int a = 0; a < 4; ++a)
#pragma unroll
        for (int b2 = 0; b2 < 4; ++b2) acc[a][b2] = (f32x4){0.f, 0.f, 0.f, 0.f};

    // A-fragment base: rec = (khkw*4 + chunk)*8 + wc*4 + tc, this lane's 8 bf16
    const bf16_t* wpbase = Wt2 + (size_t)(wc * 4) * 512 + (size_t)lane * 8;

    bf16x8 af[2][4];                             // rotating A buffers, prefetch distance 2
#pragma unroll
    for (int tc = 0; tc < 4; ++tc) af[0][tc] = *(const bf16x8*)(wpbase + AOFF(0) + (size_t)tc * 512);
#pragma unroll
    for (int tc = 0; tc < 4; ++tc) af[1][tc] = *(const bf16x8*)(wpbase + AOFF(1) + (size_t)tc * 512);

    __syncthreads();                             // chunk-0 tile ready

    CH_BODY(0);
    CH_BODY(1);
    CH_BODY(2);
    CH_BODY(3);

    // ---- epilogue: D col = lane&15 -> w, row = l4*4+i -> co  (verified mapping)
    const int h   = h0 + ws;
    const int co0 = wc * 64;
    float* obase = out + ((size_t)n * COUT) * HW + (size_t)h * WW;
#pragma unroll
    for (int tc = 0; tc < 4; ++tc) {
#pragma unroll
        for (int ts = 0; ts < 4; ++ts) {
            int w0 = ts * 16 + l15;
            if (w0 < WW) {
#pragma unroll
                for (int i = 0; i < 4; ++i) {
                    int co = co0 + tc * 16 + l4 * 4 + i;
                    obase[(size_t)co * HW + w0] = acc[tc][ts][i] + bias[co];
                }
            }
        }
    }
}

extern "C" void kernel_launch(void* const* d_in, const int* in_sizes, int n_in,
                              void* d_out, int out_size, void* d_ws, size_t ws_size,
                              hipStream_t stream) {
    const float* in   = (const float*)d_in[0];
    const float* wgt  = (const float*)d_in[1];
    const float* bias = (const float*)d_in[2];
    float* out = (float*)d_out;

    bf16_t* Wt2 = (bf16_t*)d_ws;                 // 294,912 B, fragment-major

    wtrans_kernel<<<64, 256, 0, stream>>>(wgt, Wt2);
    conv_fused_kernel<<<NIMG * ROWPAIRS, 256, 0, stream>>>(in, Wt2, bias, out);
}